// Round 1
// 6902.904 us; speedup vs baseline: 2.1461x; 2.1461x over previous
//
#include <hip/hip_runtime.h>

typedef unsigned short u16;
typedef unsigned int   u32;
typedef unsigned long long u64;
typedef __attribute__((ext_vector_type(8))) short s8v;   // 8 x bf16 (4 VGPRs)
typedef __attribute__((ext_vector_type(4))) float f4v;   // MFMA accumulator

#define DEVI __device__ __forceinline__

// ---- problem constants ----
#define B_  16
#define N_  5
#define T_  10
#define H_  512
#define E_  250
#define V_  30000
#define F_  2048
#define FH  2048   // 4H
#define H2  1024   // 2H
#define NBLK2 128  // persistent blocks: dir(2) x 64 col-groups, 2 waves each

// ---- static device scratch (no d_ws dependence) ----
__device__ u32   g_flag;                  // 1 = inputs are float32, 0 = bf16
__device__ u32   g_slot[NBLK2];           // barrier arrival epochs (per block)
__device__ u32   g_go;                    // barrier release epoch
__device__ __attribute__((aligned(64))) u16   g_H0[4*2*16*512];   // [(dir*2+par)][plane][16][512]
__device__ __attribute__((aligned(64))) u16   g_H1[4*2*16*512];
__device__ __attribute__((aligned(64))) float g_cinit[16*512];
__device__ __attribute__((aligned(64))) u16   g_A1[2*2*16*1024];  // [which][plane][16][1024]
__device__ __attribute__((aligned(64))) u16   g_X1[2*2*10*16*1024]; // [callpar][plane][row*16+b][1024]
__device__ __attribute__((aligned(64))) u16   g_OUT1[2*800*1024]; // [plane][orow][1024]
__device__ __attribute__((aligned(64))) u16   g_TOK[800*256];     // [(b*5+n)*10+r][256] bf16

DEVI f4v MFMA(s8v a, s8v b, f4v c){ return __builtin_amdgcn_mfma_f32_16x16x32_bf16(a,b,c,0,0,0); }
DEVI float bf2f(u16 u){ union{u32 i; float f;} v; v.i = ((u32)u)<<16; return v.f; }
DEVI u16 f2bf(float f){ union{float f; u32 i;} v; v.f = f; u32 i = v.i + 0x7fffu + ((v.i>>16)&1u); return (u16)(i>>16); }
DEVI float sigm(float x){ return 1.0f/(1.0f+__expf(-x)); }
DEVI float tanhfast(float x){ float e = __expf(2.0f*x); return 1.0f - 2.0f/(e+1.0f); }

DEVI s8v ld16(const u16* p){ return *(const s8v*)p; }                 // 16B-aligned, cached
DEVI s8v ld16u(const u16* p){ s8v a; __builtin_memcpy(&a, p, 16); return a; }

// coherent 16B load: relaxed system-scope atomics -> sc0 sc1, bypasses stale L1/L2,
// served by the mall (L3) which is the cross-XCD coherence point. No cache invalidation.
DEVI s8v ld16c(const u16* p){
  union{ s8v v; u64 q[2]; } r;
  u64* a = (u64*)p;
  r.q[0] = __hip_atomic_load(a,   __ATOMIC_RELAXED, __HIP_MEMORY_SCOPE_SYSTEM);
  r.q[1] = __hip_atomic_load(a+1, __ATOMIC_RELAXED, __HIP_MEMORY_SCOPE_SYSTEM);
  return r.v;
}
// coherent write-through 2B store (sc0 sc1): visible at mall, doesn't dirty local L2
DEVI void st2c(u16* p, u16 v){
  asm volatile("global_store_short %0, %1, off sc0 sc1" :: "v"(p), "v"((u32)v) : "memory");
}

// dtype-flexible element accessors (flag is wave-uniform)
DEVI u16 ldw(const void* W, size_t idx, int f32){
  return f32 ? f2bf(((const float*)W)[idx]) : ((const u16*)W)[idx];
}
DEVI float ldwf(const void* W, size_t idx, int f32){
  return f32 ? ((const float*)W)[idx] : bf2f(((const u16*)W)[idx]);
}
DEVI s8v ldA8(const void* A, size_t idx, int f32){
  if(f32){
    const float* p = (const float*)A + idx;
    s8v a;
    #pragma unroll
    for(int j=0;j<8;++j) a[j] = (short)f2bf(p[j]);
    return a;
  }
  return ld16u((const u16*)A + idx);
}
DEVI s8v gatherBf(const void* W, int ld, int row0, int col, int f32){
  s8v r;
  #pragma unroll
  for(int j=0;j<8;++j) r[j] = (short)ldw(W, (size_t)(row0+j)*ld + col, f32);
  return r;
}

// =====================  K0: dtype sniff + barrier state reset  =====================
__global__ __launch_bounds__(64) void k0(const void* img){
  int l = threadIdx.x;
  const u16* p = (const u16*)img;
  int bad = 0;
  #pragma unroll
  for(int i=0;i<4;++i){
    float v = bf2f(p[l + 64*i]);      // f32 data => half these are mantissa garbage
    if(!(fabsf(v) <= 1e4f)) bad = 1;  // catches huge exponents AND NaN
  }
  unsigned long long mb = __ballot(bad);
  g_slot[l] = 0u; g_slot[l+64] = 0u;
  if(l==0){ g_flag = (mb != 0ull) ? 1u : 0u; g_go = 0u; }
}

// =====================  K_tok: compact bf16 token-embedding table  =====================
__global__ __launch_bounds__(256) void k_tok(const int* caps, const void* emb){
  int f32 = (int)g_flag;
  int idx = blockIdx.x*256 + threadIdx.x;     // 0 .. 800*256-1
  int bnr = idx>>8, e = idx&255;
  int tok = caps[bnr];
  u16 v = (e < E_) ? ldw(emb, (size_t)tok*E_ + e, f32) : (u16)0;
  g_TOK[idx] = v;
}

// =====================  K1a: A1 = relu(img@Wh1+bh1), C1 = relu(img@Wc1+bc1) =====================
__global__ __launch_bounds__(256) void k1a(const void* img, const void* Wh1, const void* bh1,
                                           const void* Wc1, const void* bc1){
  int f32 = (int)g_flag;
  int w = threadIdx.x>>6, l = threadIdx.x&63, q = l>>4, c = l&15, m = l&15;
  int widx = blockIdx.x*4 + w;         // 0..127
  int which = widx>>6;                 // 0=h path, 1=c path
  int ct    = widx&63;                 // 64 col tiles
  const void* W    = which? Wc1 : Wh1;
  const void* bias = which? bc1 : bh1;
  int col = ct*16 + c;
  f4v acc = {0.f,0.f,0.f,0.f};
  for(int kc=0; kc<64; ++kc){
    s8v a = ldA8(img, (size_t)m*F_ + kc*32 + q*8, f32);
    s8v b = gatherBf(W, H2, kc*32+q*8, col, f32);
    acc = MFMA(a,b,acc);
  }
  float bi = ldwf(bias, col, f32);
  #pragma unroll
  for(int r=0;r<4;++r){
    float v = fmaxf(acc[r]+bi, 0.f);
    u16 hi = f2bf(v); u16 lo = f2bf(v - bf2f(hi));
    int rowb = q*4+r;
    g_A1[(size_t)(which*2+0)*B_*H2 + (size_t)rowb*H2 + col] = hi;
    g_A1[(size_t)(which*2+1)*B_*H2 + (size_t)rowb*H2 + col] = lo;
  }
}

// =====================  K1b: h,c = relu(A1@Wh2+bh2) etc; init H bufs (parity 0), cinit =====================
__global__ __launch_bounds__(256) void k1b(const void* Wh2, const void* bh2,
                                           const void* Wc2, const void* bc2){
  int f32 = (int)g_flag;
  int w = threadIdx.x>>6, l = threadIdx.x&63, q = l>>4, c = l&15, m = l&15;
  int widx = blockIdx.x*4 + w;         // 0..63
  int which = widx>>5;                 // 0=h, 1=c
  int ct    = widx&31;                 // 32 col tiles (H=512)
  const void* W    = which? Wc2 : Wh2;
  const void* bias = which? bc2 : bh2;
  const u16* Ab    = g_A1 + (size_t)which*2*B_*H2;
  int col = ct*16 + c;
  f4v acc = {0.f,0.f,0.f,0.f};
  for(int kc=0; kc<32; ++kc){
    s8v ah = ld16(Ab + (size_t)m*H2 + kc*32 + q*8);
    s8v al = ld16(Ab + (size_t)B_*H2 + (size_t)m*H2 + kc*32 + q*8);
    s8v b  = gatherBf(W, H_, kc*32+q*8, col, f32);
    acc = MFMA(ah,b,acc);
    acc = MFMA(al,b,acc);
  }
  float bi = ldwf(bias, col, f32);
  #pragma unroll
  for(int r=0;r<4;++r){
    float v = fmaxf(acc[r]+bi, 0.f);
    int rowb = q*4+r;
    if(which==0){
      u16 hi = f2bf(v); u16 lo = f2bf(v - bf2f(hi));
      #pragma unroll
      for(int dir=0; dir<2; ++dir){
        size_t base = (size_t)(dir*2+0)*16384;      // parity 0
        g_H0[base + 0*8192 + rowb*512 + col] = hi;  g_H0[base + 1*8192 + rowb*512 + col] = lo;
        g_H1[base + 0*8192 + rowb*512 + col] = hi;  g_H1[base + 1*8192 + rowb*512 + col] = lo;
      }
    } else {
      g_cinit[(size_t)rowb*H_ + col] = v;
    }
  }
}

// =====================  slot-array grid barrier: no RMW contention, NO cache-wide fences ====
// Arrival: per-block epoch store to its own slot. Block 0 wave0 aggregates (1 lane : 2 slots),
// releases via g_go. All traffic is relaxed system-scope (sc0 sc1) -> mall, L2 stays intact.
DEVI void gbar(u32 ep){
  asm volatile("s_waitcnt vmcnt(0)" ::: "memory");   // drain sc1 data stores (ack at mall)
  __syncthreads();                                    // both waves of the block done
  int tid = threadIdx.x;
  if(blockIdx.x==0){
    if(tid<64){
      if(tid==0) __hip_atomic_store(&g_slot[0], ep, __ATOMIC_RELAXED, __HIP_MEMORY_SCOPE_SYSTEM);
      for(;;){
        u32 a = __hip_atomic_load(&g_slot[tid],    __ATOMIC_RELAXED, __HIP_MEMORY_SCOPE_SYSTEM);
        u32 b = __hip_atomic_load(&g_slot[tid+64], __ATOMIC_RELAXED, __HIP_MEMORY_SCOPE_SYSTEM);
        if(__all(a>=ep && b>=ep)) break;
        __builtin_amdgcn_s_sleep(1);
      }
      if(tid==0) __hip_atomic_store(&g_go, ep, __ATOMIC_RELAXED, __HIP_MEMORY_SCOPE_SYSTEM);
    }
  } else {
    if(tid==0) __hip_atomic_store(&g_slot[blockIdx.x], ep, __ATOMIC_RELAXED, __HIP_MEMORY_SCOPE_SYSTEM);
    if(tid<64){
      while(__hip_atomic_load(&g_go, __ATOMIC_RELAXED, __HIP_MEMORY_SCOPE_SYSTEM) < ep)
        __builtin_amdgcn_s_sleep(1);
    }
  }
  __syncthreads();
}

// gate combine: acc holds G[batch=4q+r][col c], cols = gate(c>>2) x hcol(c&3).
DEVI float gate_combine(f4v acc, float& cs, int l){
  int base = (l & 48) | (l & 3);
  int sel  = (l >> 2) & 3;
  float G[4];
  #pragma unroll
  for(int gg=0; gg<4; ++gg){
    int src = base | (gg<<2);
    float a0 = __shfl(acc[0], src, 64);
    float a1 = __shfl(acc[1], src, 64);
    float a2 = __shfl(acc[2], src, 64);
    float a3 = __shfl(acc[3], src, 64);
    float x = (sel&1)? a1 : a0;
    float y = (sel&1)? a3 : a2;
    G[gg] = (sel&2)? y : x;
  }
  float iG = sigm(G[0]);
  float fG = sigm(G[1]);
  float gG = tanhfast(G[2]);
  float oG = sigm(G[3]);
  cs = fG*cs + iG*gG;
  return oG * tanhfast(cs);
}

// =====================  K2: persistent pipelined bilstm2 x 50  =====================
// 128 blocks x 128 threads (2 waves). Block: dir = blk>=64, 8 h-cols (two 16-gcol MFMA tiles).
// wave0 = layer-0 engine (weights in VGPRs), wave1 = layer-1 engine lagged one call
// (folded [Wih1;Whh1] in 96KB LDS). 285 supersteps instead of 550 barrier steps.
// Recurrent state (H0/H1/X1) exchanged via sc0sc1 write-through stores + system-scope
// bypassing loads (pipelined, depth 8) -- no threadfence, weights/TOK stay L2-cached.
__global__ __launch_bounds__(128) void k2(const void* Wih0f, const void* Whh0f, const void* b0f,
                                          const void* Wih0b, const void* Whh0b, const void* b0b,
                                          const void* Wih1f, const void* Whh1f, const void* b1f,
                                          const void* Wih1b, const void* Whh1b, const void* b1b){
  __shared__ u16 sw[2*24576];                  // 96 KB: [tile][kc48][c16][q4][j8]
  int f32 = (int)g_flag;
  int tid = threadIdx.x;
  int wv  = tid>>6;                            // 0 = layer-0 wave, 1 = layer-1 wave
  int l   = tid&63;
  int q = l>>4, c = l&15, m = l&15;
  int blk = blockIdx.x;
  int dir = blk>>6; int blkd = blk&63;
  int hb  = blkd*8;                            // 8 owned h-cols
  int gc0 = (c>>2)*512 + hb + (c&3);           // lane's G-column, tile 0
  int gc1 = gc0 + 4;                           // tile 1
  int bo  = q*4 + (c>>2);                      // owned batch row
  int hc0 = hb + (c&3), hc1 = hc0 + 4;         // owned h-cols

  const void* Wih0 = dir? Wih0b : Wih0f;
  const void* Whh0 = dir? Whh0b : Whh0f;
  const void* b0   = dir? b0b   : b0f;
  const void* Wih1 = dir? Wih1b : Wih1f;
  const void* Whh1 = dir? Whh1b : Whh1f;
  const void* b1   = dir? b1b   : b1f;

  // ---- layer-1 B-fragments for both tiles in LDS ----
  for(int tt=0; tt<2; ++tt){
    int gb = hb + tt*4;
    for(int ii=tid; ii<24576; ii+=128){
      int kc=ii>>9, rem=ii&511, cc=rem>>5, qq=(rem>>3)&3, j=ii&7;
      int gc = (cc>>2)*512 + gb + (cc&3);
      int rowk = kc*32+qq*8+j;
      sw[tt*24576+ii] = (rowk < H2) ? ldw(Wih1, (size_t)rowk*FH + gc, f32)
                                    : ldw(Whh1, (size_t)(rowk-H2)*FH + gc, f32);
    }
  }

  // ---- per-wave persistent state ----
  s8v w0a[16], w0b[16], wxa[8], wxb[8];        // wave0 only: layer-0 B-frags in regs
  float cA0=0.f, cA1=0.f, biasA0=0.f, biasA1=0.f;   // wave0 (layer-0 cell state)
  float cB0=0.f, cB1=0.f, biasB0=0.f, biasB1=0.f;   // wave1 (layer-1 cell state)
  if(wv==0){
    #pragma unroll
    for(int kc=0;kc<16;++kc){
      #pragma unroll
      for(int j=0;j<8;++j){
        int rowk = kc*32+q*8+j;
        w0a[kc][j] = (short)ldw(Whh0, (size_t)rowk*FH + gc0, f32);
        w0b[kc][j] = (short)ldw(Whh0, (size_t)rowk*FH + gc1, f32);
      }
    }
    #pragma unroll
    for(int kc=0;kc<8;++kc){
      #pragma unroll
      for(int j=0;j<8;++j){
        int rowk = kc*32+q*8+j;
        wxa[kc][j] = (rowk<E_)? (short)ldw(Wih0, (size_t)rowk*FH + gc0, f32) : (short)0;
        wxb[kc][j] = (rowk<E_)? (short)ldw(Wih0, (size_t)rowk*FH + gc1, f32) : (short)0;
      }
    }
    biasA0 = ldwf(b0, gc0, f32); biasA1 = ldwf(b0, gc1, f32);
    cA0 = g_cinit[(size_t)bo*H_ + hc0]; cA1 = g_cinit[(size_t)bo*H_ + hc1];
  } else {
    biasB0 = ldwf(b1, gc0, f32); biasB1 = ldwf(b1, gc1, f32);
    cB0 = g_cinit[(size_t)bo*H_ + hc0]; cB1 = g_cinit[(size_t)bo*H_ + hc1];
  }
  __syncthreads();

  u32 ep = 0;
  int p0 = 0, p1 = 0;
  // superstep schedule: layer-0 runs call k, layer-1 runs call k-1 (lengths
  // are non-decreasing so layer-1 never lags more than the current call).
  // k==50 is the pure layer-1 tail for call 49.
  for(int k=0; k<=50; ++k){
    int Lk = (k<50) ? (k/5 + 1) : 10;
    int Lp = (k==0) ? 0 : ((k-1)/5 + 1);
    for(int s=0; s<Lk; ++s){
      if(wv==0){
        if(k<50){
          int n = k - (k/5)*5;
          int row = dir ? (Lk-1-s) : s;
          const u16* er = g_TOK + ((size_t)(m*N_ + n)*T_ + row)*256;
          const u16* Hr = g_H0 + (size_t)(dir*2 + p0)*16384;
          f4v A0 = {biasA0,biasA0,biasA0,biasA0};
          f4v A1 = {biasA1,biasA1,biasA1,biasA1};
          #pragma unroll
          for(int kc=0;kc<8;++kc){
            s8v a = ld16(er + kc*32 + q*8);               // TOK: read-only, L2-cached
            A0 = MFMA(a, wxa[kc], A0); A1 = MFMA(a, wxb[kc], A1);
          }
          // pipelined coherent H stream: 32 frags (kc x {hi,lo}), depth 8
          s8v hst[8];
          #pragma unroll
          for(int f=0;f<8;++f)
            hst[f] = ld16c(Hr + ((f&1)? 8192u:0u) + (size_t)m*H_ + (f>>1)*32 + q*8);
          #pragma unroll
          for(int f=0;f<32;++f){
            s8v hv = hst[f&7];
            if(f+8<32){
              int g2 = f+8;
              hst[f&7] = ld16c(Hr + ((g2&1)? 8192u:0u) + (size_t)m*H_ + (g2>>1)*32 + q*8);
            }
            int kc = f>>1;
            A0 = MFMA(hv, w0a[kc], A0); A1 = MFMA(hv, w0b[kc], A1);
          }
          float hn0 = gate_combine(A0, cA0, l);
          float hn1 = gate_combine(A1, cA1, l);
          u16 h0h=f2bf(hn0), h0l=f2bf(hn0 - bf2f(h0h));
          u16 h1h=f2bf(hn1), h1l=f2bf(hn1 - bf2f(h1h));
          u16* Hw = g_H0 + (size_t)(dir*2 + (p0^1))*16384;
          st2c(Hw + (size_t)bo*H_ + hc0, h0h); st2c(Hw + 8192 + (size_t)bo*H_ + hc0, h0l);
          st2c(Hw + (size_t)bo*H_ + hc1, h1h); st2c(Hw + 8192 + (size_t)bo*H_ + hc1, h1l);
          u16* Xw = g_X1 + (size_t)(k&1)*327680;          // call-parity double buffer
          size_t xr = ((size_t)row*16 + bo)*H2 + dir*H_;
          st2c(Xw + xr + hc0, h0h); st2c(Xw + 163840 + xr + hc0, h0l);
          st2c(Xw + xr + hc1, h1h); st2c(Xw + 163840 + xr + hc1, h1l);
          p0 ^= 1;
        }
      } else {
        if(k>0 && s<Lp){
          int km = k-1;
          int n = km - (km/5)*5;
          int row = dir ? (Lp-1-s) : s;
          const u16* Xr  = g_X1 + (size_t)(km&1)*327680 + ((size_t)row*16)*H2;
          const u16* Xr2 = Xr + 163840;
          const u16* Hr  = g_H1 + (size_t)(dir*2 + p1)*16384;
          f4v A0 = {biasB0,biasB0,biasB0,biasB0};
          f4v A1 = {biasB1,biasB1,biasB1,biasB1};
          // pipelined coherent stream: kc 0..31 = X1 (K=1024), kc 32..47 = H1 (K=512),
          // each kc has {hi,lo}; depth 8 kc-pairs (32 u64 loads in flight)
          s8v sh[8], sl[8];
          #pragma unroll
          for(int kc=0;kc<8;++kc){
            sh[kc] = ld16c(Xr  + (size_t)m*H2 + kc*32 + q*8);
            sl[kc] = ld16c(Xr2 + (size_t)m*H2 + kc*32 + q*8);
          }
          #pragma unroll
          for(int kc=0;kc<48;++kc){
            s8v xh = sh[kc&7], xl = sl[kc&7];
            if(kc+8<48){
              int kn = kc+8;
              const u16* ph = (kn<32)? (Xr  + (size_t)m*H2 + kn*32 + q*8)
                                     : (Hr  + (size_t)m*H_ + (kn-32)*32 + q*8);
              const u16* pl = (kn<32)? (Xr2 + (size_t)m*H2 + kn*32 + q*8)
                                     : (Hr + 8192 + (size_t)m*H_ + (kn-32)*32 + q*8);
              sh[kc&7] = ld16c(ph);
              sl[kc&7] = ld16c(pl);
            }
            s8v bf0 = ld16(sw +         kc*512 + c*32 + q*8);
            s8v bf1 = ld16(sw + 24576 + kc*512 + c*32 + q*8);
            A0 = MFMA(xh, bf0, A0); A0 = MFMA(xl, bf0, A0);
            A1 = MFMA(xh, bf1, A1); A1 = MFMA(xl, bf1, A1);
          }
          float hn0 = gate_combine(A0, cB0, l);
          float hn1 = gate_combine(A1, cB1, l);
          u16 h0h=f2bf(hn0), h0l=f2bf(hn0 - bf2f(h0h));
          u16 h1h=f2bf(hn1), h1l=f2bf(hn1 - bf2f(h1h));
          u16* Hw = g_H1 + (size_t)(dir*2 + (p1^1))*16384;
          st2c(Hw + (size_t)bo*H_ + hc0, h0h); st2c(Hw + 8192 + (size_t)bo*H_ + hc0, h0l);
          st2c(Hw + (size_t)bo*H_ + hc1, h1h); st2c(Hw + 8192 + (size_t)bo*H_ + hc1, h1l);
          size_t orow = (size_t)(n*10 + row)*16 + bo;      // OUT1: plain cached stores (read by k3)
          g_OUT1[orow*H2 + dir*H_ + hc0] = h0h;
          g_OUT1[(size_t)800*H2 + orow*H2 + dir*H_ + hc0] = h0l;
          g_OUT1[orow*H2 + dir*H_ + hc1] = h1h;
          g_OUT1[(size_t)800*H2 + orow*H2 + dir*H_ + hc1] = h1l;
          p1 ^= 1;
        }
      }
      ++ep;
      gbar(ep);
    }
  }
}

// =====================  K3: out = OUT1(800x1024 hi/lo) @ Wfc(1024x30000) + bfc =====================
__global__ __launch_bounds__(256,1) void k3(const void* Wfc, const void* bfc, void* out){
  int f32 = (int)g_flag;
  int w = threadIdx.x>>6, l = threadIdx.x&63, q = l>>4, c = l&15, m = l&15;
  int ct = blockIdx.x*4 + w;
  if(ct >= 1875) return;
  int col = ct*16 + c;
  s8v bfr[32];
  #pragma unroll
  for(int kc=0; kc<32; ++kc){
    #pragma unroll
    for(int j=0;j<8;++j) bfr[kc][j] = (short)ldw(Wfc, (size_t)(kc*32+q*8+j)*V_ + col, f32);
  }
  float bi = ldwf(bfc, col, f32);
  for(int rt=0; rt<50; ++rt){
    f4v acc = {0.f,0.f,0.f,0.f};
    const u16* Ah = g_OUT1 + (size_t)(rt*16 + m)*H2;
    const u16* Al = Ah + (size_t)800*H2;
    #pragma unroll
    for(int kc=0; kc<32; ++kc){
      acc = MFMA(ld16(Ah + kc*32 + q*8), bfr[kc], acc);
      acc = MFMA(ld16(Al + kc*32 + q*8), bfr[kc], acc);
    }
    if(f32){
      float* o = (float*)out;
      #pragma unroll
      for(int r=0;r<4;++r) o[(size_t)(rt*16 + q*4 + r)*V_ + col] = acc[r] + bi;
    } else {
      u16* o = (u16*)out;
      #pragma unroll
      for(int r=0;r<4;++r) o[(size_t)(rt*16 + q*4 + r)*V_ + col] = f2bf(acc[r] + bi);
    }
  }
}

// =====================  launcher  =====================
extern "C" void kernel_launch(void* const* d_in, const int* in_sizes, int n_in,
                              void* d_out, int out_size, void* d_ws, size_t ws_size,
                              hipStream_t stream){
  (void)in_sizes; (void)n_in; (void)out_size; (void)d_ws; (void)ws_size;
  const void* img  = d_in[0];
  const int*  caps = (const int*)d_in[1];
  const void* Wh1=d_in[2],  *bh1=d_in[3];
  const void* Wh2=d_in[4],  *bh2=d_in[5];
  const void* Wc1=d_in[6],  *bc1=d_in[7];
  const void* Wc2=d_in[8],  *bc2=d_in[9];
  const void* emb=d_in[10];
  const void* Wih0f=d_in[11], *Whh0f=d_in[12], *b0f=d_in[13];
  const void* Wih0b=d_in[14], *Whh0b=d_in[15], *b0b=d_in[16];
  const void* Wih1f=d_in[17], *Whh1f=d_in[18], *b1f=d_in[19];
  const void* Wih1b=d_in[20], *Whh1b=d_in[21], *b1b=d_in[22];
  const void* Wfc=d_in[23],  *bfc=d_in[24];

  hipLaunchKernelGGL(k0,    dim3(1),     dim3(64),  0, stream, img);
  hipLaunchKernelGGL(k_tok, dim3(800),   dim3(256), 0, stream, caps, emb);
  hipLaunchKernelGGL(k1a,   dim3(32),    dim3(256), 0, stream, img, Wh1, bh1, Wc1, bc1);
  hipLaunchKernelGGL(k1b,   dim3(16),    dim3(256), 0, stream, Wh2, bh2, Wc2, bc2);
  hipLaunchKernelGGL(k2,    dim3(NBLK2), dim3(128), 0, stream,
                     Wih0f, Whh0f, b0f, Wih0b, Whh0b, b0b,
                     Wih1f, Whh1f, b1f, Wih1b, Whh1b, b1b);
  hipLaunchKernelGGL(k3,    dim3(469),   dim3(256), 0, stream, Wfc, bfc, d_out);
}

// Round 2
// 5656.651 us; speedup vs baseline: 2.6189x; 1.2203x over previous
//
#include <hip/hip_runtime.h>

typedef unsigned short u16;
typedef unsigned int   u32;
typedef unsigned long long u64;
typedef __attribute__((ext_vector_type(8))) short s8v;   // 8 x bf16 (4 VGPRs)
typedef __attribute__((ext_vector_type(4))) float f4v;   // MFMA accumulator

#define DEVI __device__ __forceinline__

// ---- problem constants ----
#define B_  16
#define N_  5
#define T_  10
#define H_  512
#define E_  250
#define V_  30000
#define F_  2048
#define FH  2048   // 4H
#define H2  1024   // 2H
#define NCOMP 128  // compute blocks: dir(2) x 64 col-groups, 2 waves each
#define EPMAX 285u // total supersteps

// ---- static device scratch (no d_ws dependence) ----
__device__ u32   g_flag;                  // 1 = inputs are float32, 0 = bf16
__device__ u32   g_slot[NCOMP];           // barrier arrival epochs (per block)
__device__ u32   g_go;                    // barrier release epoch
__device__ __attribute__((aligned(64))) u16   g_H0[4*2*16*512];   // [(dir*2+par)][plane][16][512]
__device__ __attribute__((aligned(64))) u16   g_H1[4*2*16*512];
__device__ __attribute__((aligned(64))) float g_cinit[16*512];
__device__ __attribute__((aligned(64))) u16   g_A1[2*2*16*1024];  // [which][plane][16][1024]
__device__ __attribute__((aligned(64))) u16   g_X1[2*2*10*16*1024]; // [callpar][plane][row*16+b][1024]
__device__ __attribute__((aligned(64))) u16   g_OUT1[2*800*1024]; // [plane][orow][1024]
__device__ __attribute__((aligned(64))) u16   g_TOK[800*256];     // [(b*5+n)*10+r][256] bf16

DEVI f4v MFMA(s8v a, s8v b, f4v c){ return __builtin_amdgcn_mfma_f32_16x16x32_bf16(a,b,c,0,0,0); }
DEVI float bf2f(u16 u){ union{u32 i; float f;} v; v.i = ((u32)u)<<16; return v.f; }
DEVI u16 f2bf(float f){ union{float f; u32 i;} v; v.f = f; u32 i = v.i + 0x7fffu + ((v.i>>16)&1u); return (u16)(i>>16); }
DEVI float sigm(float x){ return 1.0f/(1.0f+__expf(-x)); }
DEVI float tanhfast(float x){ float e = __expf(2.0f*x); return 1.0f - 2.0f/(e+1.0f); }

DEVI s8v ld16(const u16* p){ return *(const s8v*)p; }                 // 16B-aligned, cached
DEVI s8v ld16u(const u16* p){ s8v a; __builtin_memcpy(&a, p, 16); return a; }

// coherent write-through 2B store (sc0 sc1): visible at mall, never dirty in L2
DEVI void st2c(u16* p, u16 v){
  asm volatile("global_store_short %0, %1, off sc0 sc1" :: "v"(p), "v"((u32)v) : "memory");
}

// dtype-flexible element accessors (flag is wave-uniform)
DEVI u16 ldw(const void* W, size_t idx, int f32){
  return f32 ? f2bf(((const float*)W)[idx]) : ((const u16*)W)[idx];
}
DEVI float ldwf(const void* W, size_t idx, int f32){
  return f32 ? ((const float*)W)[idx] : bf2f(((const u16*)W)[idx]);
}
DEVI s8v ldA8(const void* A, size_t idx, int f32){
  if(f32){
    const float* p = (const float*)A + idx;
    s8v a;
    #pragma unroll
    for(int j=0;j<8;++j) a[j] = (short)f2bf(p[j]);
    return a;
  }
  return ld16u((const u16*)A + idx);
}
DEVI s8v gatherBf(const void* W, int ld, int row0, int col, int f32){
  s8v r;
  #pragma unroll
  for(int j=0;j<8;++j) r[j] = (short)ldw(W, (size_t)(row0+j)*ld + col, f32);
  return r;
}

// =====================  K0: dtype sniff + barrier state reset  =====================
__global__ __launch_bounds__(64) void k0(const void* img){
  int l = threadIdx.x;
  const u16* p = (const u16*)img;
  int bad = 0;
  #pragma unroll
  for(int i=0;i<4;++i){
    float v = bf2f(p[l + 64*i]);      // f32 data => half these are mantissa garbage
    if(!(fabsf(v) <= 1e4f)) bad = 1;  // catches huge exponents AND NaN
  }
  unsigned long long mb = __ballot(bad);
  g_slot[l] = 0u; g_slot[l+64] = 0u;
  if(l==0){ g_flag = (mb != 0ull) ? 1u : 0u; g_go = 0u; }
}

// =====================  K_tok: compact bf16 token-embedding table  =====================
__global__ __launch_bounds__(256) void k_tok(const int* caps, const void* emb){
  int f32 = (int)g_flag;
  int idx = blockIdx.x*256 + threadIdx.x;     // 0 .. 800*256-1
  int bnr = idx>>8, e = idx&255;
  int tok = caps[bnr];
  u16 v = (e < E_) ? ldw(emb, (size_t)tok*E_ + e, f32) : (u16)0;
  g_TOK[idx] = v;
}

// =====================  K1a: A1 = relu(img@Wh1+bh1), C1 = relu(img@Wc1+bc1) =====================
__global__ __launch_bounds__(256) void k1a(const void* img, const void* Wh1, const void* bh1,
                                           const void* Wc1, const void* bc1){
  int f32 = (int)g_flag;
  int w = threadIdx.x>>6, l = threadIdx.x&63, q = l>>4, c = l&15, m = l&15;
  int widx = blockIdx.x*4 + w;         // 0..127
  int which = widx>>6;                 // 0=h path, 1=c path
  int ct    = widx&63;                 // 64 col tiles
  const void* W    = which? Wc1 : Wh1;
  const void* bias = which? bc1 : bh1;
  int col = ct*16 + c;
  f4v acc = {0.f,0.f,0.f,0.f};
  for(int kc=0; kc<64; ++kc){
    s8v a = ldA8(img, (size_t)m*F_ + kc*32 + q*8, f32);
    s8v b = gatherBf(W, H2, kc*32+q*8, col, f32);
    acc = MFMA(a,b,acc);
  }
  float bi = ldwf(bias, col, f32);
  #pragma unroll
  for(int r=0;r<4;++r){
    float v = fmaxf(acc[r]+bi, 0.f);
    u16 hi = f2bf(v); u16 lo = f2bf(v - bf2f(hi));
    int rowb = q*4+r;
    g_A1[(size_t)(which*2+0)*B_*H2 + (size_t)rowb*H2 + col] = hi;
    g_A1[(size_t)(which*2+1)*B_*H2 + (size_t)rowb*H2 + col] = lo;
  }
}

// =====================  K1b: h,c = relu(A1@Wh2+bh2) etc; init H bufs (parity 0), cinit =====================
__global__ __launch_bounds__(256) void k1b(const void* Wh2, const void* bh2,
                                           const void* Wc2, const void* bc2){
  int f32 = (int)g_flag;
  int w = threadIdx.x>>6, l = threadIdx.x&63, q = l>>4, c = l&15, m = l&15;
  int widx = blockIdx.x*4 + w;         // 0..63
  int which = widx>>5;                 // 0=h, 1=c
  int ct    = widx&31;                 // 32 col tiles (H=512)
  const void* W    = which? Wc2 : Wh2;
  const void* bias = which? bc2 : bh2;
  const u16* Ab    = g_A1 + (size_t)which*2*B_*H2;
  int col = ct*16 + c;
  f4v acc = {0.f,0.f,0.f,0.f};
  for(int kc=0; kc<32; ++kc){
    s8v ah = ld16(Ab + (size_t)m*H2 + kc*32 + q*8);
    s8v al = ld16(Ab + (size_t)B_*H2 + (size_t)m*H2 + kc*32 + q*8);
    s8v b  = gatherBf(W, H_, kc*32+q*8, col, f32);
    acc = MFMA(ah,b,acc);
    acc = MFMA(al,b,acc);
  }
  float bi = ldwf(bias, col, f32);
  #pragma unroll
  for(int r=0;r<4;++r){
    float v = fmaxf(acc[r]+bi, 0.f);
    int rowb = q*4+r;
    if(which==0){
      u16 hi = f2bf(v); u16 lo = f2bf(v - bf2f(hi));
      #pragma unroll
      for(int dir=0; dir<2; ++dir){
        size_t base = (size_t)(dir*2+0)*16384;      // parity 0
        g_H0[base + 0*8192 + rowb*512 + col] = hi;  g_H0[base + 1*8192 + rowb*512 + col] = lo;
        g_H1[base + 0*8192 + rowb*512 + col] = hi;  g_H1[base + 1*8192 + rowb*512 + col] = lo;
      }
    } else {
      g_cinit[(size_t)rowb*H_ + col] = v;
    }
  }
}

// ============ split barrier: arrive (slot store) / wait (poll go) + agent-acquire inv ======
// Writers: st2c (sc0sc1 write-through -> fresh at mall). Arrival after vmcnt(0) drain.
// Coordinator block (blockIdx==NCOMP) aggregates slots and releases g_go.
// Readers: after release, ONE agent-scope acquire fence per block (buffer_inv sc1) makes
// plain cached loads coherent; same-XCD blocks then share L2 refills (8-16x dedup vs bypass).
DEVI void bar_arrive(u32 ep){
  asm volatile("s_waitcnt vmcnt(0)" ::: "memory");   // data stores acked at mall
  __syncthreads();                                    // both waves of the block done
  if(threadIdx.x==0)
    __hip_atomic_store(&g_slot[blockIdx.x], ep, __ATOMIC_RELAXED, __HIP_MEMORY_SCOPE_SYSTEM);
}
DEVI void bar_wait(u32 ep){
  if(threadIdx.x<64){
    while(__hip_atomic_load(&g_go, __ATOMIC_RELAXED, __HIP_MEMORY_SCOPE_SYSTEM) < ep)
      __builtin_amdgcn_s_sleep(1);
  }
  __syncthreads();
  if(threadIdx.x<64)
    __builtin_amdgcn_fence(__ATOMIC_ACQUIRE, "agent");  // buffer_inv sc1: L1+L2 invalidate
  __syncthreads();
}

// gate combine: acc holds G[batch=4q+r][col c], cols = gate(c>>2) x hcol(c&3).
DEVI float gate_combine(f4v acc, float& cs, int l){
  int base = (l & 48) | (l & 3);
  int sel  = (l >> 2) & 3;
  float G[4];
  #pragma unroll
  for(int gg=0; gg<4; ++gg){
    int src = base | (gg<<2);
    float a0 = __shfl(acc[0], src, 64);
    float a1 = __shfl(acc[1], src, 64);
    float a2 = __shfl(acc[2], src, 64);
    float a3 = __shfl(acc[3], src, 64);
    float x = (sel&1)? a1 : a0;
    float y = (sel&1)? a3 : a2;
    G[gg] = (sel&2)? y : x;
  }
  float iG = sigm(G[0]);
  float fG = sigm(G[1]);
  float gG = tanhfast(G[2]);
  float oG = sigm(G[3]);
  cs = fG*cs + iG*gG;
  return oG * tanhfast(cs);
}

// =====================  K2: persistent pipelined bilstm2 x 50  =====================
// 128 compute blocks x 128 threads (2 waves) + 1 coordinator block.
// Block: dir = blk>=64, 8 h-cols. wave0 = layer-0 engine (weights in VGPRs), wave1 =
// layer-1 engine lagged one call (folded [Wih1;Whh1] in 96KB LDS). 285 supersteps.
// Coherence: write-through stores + per-superstep agent acquire-inv + plain cached loads
// (compiler-pipelined, L2-deduped) -- no atomic-load serialization.
__global__ __launch_bounds__(128) void k2(const void* Wih0f, const void* Whh0f, const void* b0f,
                                          const void* Wih0b, const void* Whh0b, const void* b0b,
                                          const void* Wih1f, const void* Whh1f, const void* b1f,
                                          const void* Wih1b, const void* Whh1b, const void* b1b){
  __shared__ u16 sw[2*24576];                  // 96 KB: [tile][kc48][c16][q4][j8]
  int tid = threadIdx.x;
  int blk = blockIdx.x;

  // ---- coordinator block: aggregate arrivals, release epochs ----
  if(blk==NCOMP){
    if(tid<64){
      for(u32 e2=1; e2<=EPMAX; ++e2){
        for(;;){
          u32 a = __hip_atomic_load(&g_slot[tid],    __ATOMIC_RELAXED, __HIP_MEMORY_SCOPE_SYSTEM);
          u32 b = __hip_atomic_load(&g_slot[tid+64], __ATOMIC_RELAXED, __HIP_MEMORY_SCOPE_SYSTEM);
          if(__all(a>=e2 && b>=e2)) break;
          __builtin_amdgcn_s_sleep(1);
        }
        if(tid==0)
          __hip_atomic_store(&g_go, e2, __ATOMIC_RELAXED, __HIP_MEMORY_SCOPE_SYSTEM);
      }
    }
    return;
  }

  int f32 = (int)g_flag;
  int wv  = tid>>6;                            // 0 = layer-0 wave, 1 = layer-1 wave
  int l   = tid&63;
  int q = l>>4, c = l&15, m = l&15;
  int dir = blk>>6; int blkd = blk&63;
  int hb  = blkd*8;                            // 8 owned h-cols
  int gc0 = (c>>2)*512 + hb + (c&3);           // lane's G-column, tile 0
  int gc1 = gc0 + 4;                           // tile 1
  int bo  = q*4 + (c>>2);                      // owned batch row
  int hc0 = hb + (c&3), hc1 = hc0 + 4;         // owned h-cols

  const void* Wih0 = dir? Wih0b : Wih0f;
  const void* Whh0 = dir? Whh0b : Whh0f;
  const void* b0   = dir? b0b   : b0f;
  const void* Wih1 = dir? Wih1b : Wih1f;
  const void* Whh1 = dir? Whh1b : Whh1f;
  const void* b1   = dir? b1b   : b1f;

  // ---- layer-1 B-fragments for both tiles in LDS ----
  for(int tt=0; tt<2; ++tt){
    int gb = hb + tt*4;
    for(int ii=tid; ii<24576; ii+=128){
      int kc=ii>>9, rem=ii&511, cc=rem>>5, qq=(rem>>3)&3, j=ii&7;
      int gc = (cc>>2)*512 + gb + (cc&3);
      int rowk = kc*32+qq*8+j;
      sw[tt*24576+ii] = (rowk < H2) ? ldw(Wih1, (size_t)rowk*FH + gc, f32)
                                    : ldw(Whh1, (size_t)(rowk-H2)*FH + gc, f32);
    }
  }

  // ---- per-wave persistent state ----
  s8v w0a[16], w0b[16], wxa[8], wxb[8];        // wave0 only: layer-0 B-frags in regs
  float cA0=0.f, cA1=0.f, biasA0=0.f, biasA1=0.f;   // wave0 (layer-0 cell state)
  float cB0=0.f, cB1=0.f, biasB0=0.f, biasB1=0.f;   // wave1 (layer-1 cell state)
  if(wv==0){
    #pragma unroll
    for(int kc=0;kc<16;++kc){
      #pragma unroll
      for(int j=0;j<8;++j){
        int rowk = kc*32+q*8+j;
        w0a[kc][j] = (short)ldw(Whh0, (size_t)rowk*FH + gc0, f32);
        w0b[kc][j] = (short)ldw(Whh0, (size_t)rowk*FH + gc1, f32);
      }
    }
    #pragma unroll
    for(int kc=0;kc<8;++kc){
      #pragma unroll
      for(int j=0;j<8;++j){
        int rowk = kc*32+q*8+j;
        wxa[kc][j] = (rowk<E_)? (short)ldw(Wih0, (size_t)rowk*FH + gc0, f32) : (short)0;
        wxb[kc][j] = (rowk<E_)? (short)ldw(Wih0, (size_t)rowk*FH + gc1, f32) : (short)0;
      }
    }
    biasA0 = ldwf(b0, gc0, f32); biasA1 = ldwf(b0, gc1, f32);
    cA0 = g_cinit[(size_t)bo*H_ + hc0]; cA1 = g_cinit[(size_t)bo*H_ + hc1];
  } else {
    biasB0 = ldwf(b1, gc0, f32); biasB1 = ldwf(b1, gc1, f32);
    cB0 = g_cinit[(size_t)bo*H_ + hc0]; cB1 = g_cinit[(size_t)bo*H_ + hc1];
  }
  __syncthreads();

  u32 ep = 0;
  int p0 = 0, p1 = 0;
  // superstep schedule: layer-0 runs call k, layer-1 runs call k-1 (lengths
  // are non-decreasing so layer-1 never lags more than the current call).
  // k==50 is the pure layer-1 tail for call 49.
  for(int k=0; k<=50; ++k){
    int Lk = (k<50) ? (k/5 + 1) : 10;
    int Lp = (k==0) ? 0 : ((k-1)/5 + 1);
    for(int s=0; s<Lk; ++s){
      if(wv==0){
        if(k<50){
          int n = k - (k/5)*5;
          int row = dir ? (Lk-1-s) : s;
          const u16* er = g_TOK + ((size_t)(m*N_ + n)*T_ + row)*256;
          const u16* Hr = g_H0 + (size_t)(dir*2 + p0)*16384;
          f4v A0 = {biasA0,biasA0,biasA0,biasA0};
          f4v A1 = {biasA1,biasA1,biasA1,biasA1};
          #pragma unroll
          for(int kc=0;kc<8;++kc){
            s8v a = ld16(er + kc*32 + q*8);
            A0 = MFMA(a, wxa[kc], A0); A1 = MFMA(a, wxb[kc], A1);
          }
          // pipelined H stream: 32 frags (kc x {hi,lo}), rotation depth 8
          s8v hst[8];
          #pragma unroll
          for(int f=0;f<8;++f)
            hst[f] = ld16(Hr + ((f&1)? 8192u:0u) + (size_t)m*H_ + (f>>1)*32 + q*8);
          #pragma unroll
          for(int f=0;f<32;++f){
            s8v hv = hst[f&7];
            if(f+8<32){
              int g2 = f+8;
              hst[f&7] = ld16(Hr + ((g2&1)? 8192u:0u) + (size_t)m*H_ + (g2>>1)*32 + q*8);
            }
            int kc = f>>1;
            A0 = MFMA(hv, w0a[kc], A0); A1 = MFMA(hv, w0b[kc], A1);
          }
          float hn0 = gate_combine(A0, cA0, l);
          float hn1 = gate_combine(A1, cA1, l);
          u16 h0h=f2bf(hn0), h0l=f2bf(hn0 - bf2f(h0h));
          u16 h1h=f2bf(hn1), h1l=f2bf(hn1 - bf2f(h1h));
          u16* Hw = g_H0 + (size_t)(dir*2 + (p0^1))*16384;
          st2c(Hw + (size_t)bo*H_ + hc0, h0h); st2c(Hw + 8192 + (size_t)bo*H_ + hc0, h0l);
          st2c(Hw + (size_t)bo*H_ + hc1, h1h); st2c(Hw + 8192 + (size_t)bo*H_ + hc1, h1l);
          u16* Xw = g_X1 + (size_t)(k&1)*327680;          // call-parity double buffer
          size_t xr = ((size_t)row*16 + bo)*H2 + dir*H_;
          st2c(Xw + xr + hc0, h0h); st2c(Xw + 163840 + xr + hc0, h0l);
          st2c(Xw + xr + hc1, h1h); st2c(Xw + 163840 + xr + hc1, h1l);
          p0 ^= 1;
        }
      } else {
        if(k>0 && s<Lp){
          int km = k-1;
          int n = km - (km/5)*5;
          int row = dir ? (Lp-1-s) : s;
          const u16* Xr  = g_X1 + (size_t)(km&1)*327680 + ((size_t)row*16)*H2;
          const u16* Xr2 = Xr + 163840;
          const u16* Hr  = g_H1 + (size_t)(dir*2 + p1)*16384;
          f4v A0 = {biasB0,biasB0,biasB0,biasB0};
          f4v A1 = {biasB1,biasB1,biasB1,biasB1};
          // pipelined stream: kc 0..31 = X1 (K=1024), kc 32..47 = H1 (K=512),
          // each kc has {hi,lo}; rotation depth 8 kc-pairs
          s8v sh[8], sl[8];
          #pragma unroll
          for(int kc=0;kc<8;++kc){
            sh[kc] = ld16(Xr  + (size_t)m*H2 + kc*32 + q*8);
            sl[kc] = ld16(Xr2 + (size_t)m*H2 + kc*32 + q*8);
          }
          #pragma unroll
          for(int kc=0;kc<48;++kc){
            s8v xh = sh[kc&7], xl = sl[kc&7];
            if(kc+8<48){
              int kn = kc+8;
              const u16* ph = (kn<32)? (Xr  + (size_t)m*H2 + kn*32 + q*8)
                                     : (Hr  + (size_t)m*H_ + (kn-32)*32 + q*8);
              const u16* pl = (kn<32)? (Xr2 + (size_t)m*H2 + kn*32 + q*8)
                                     : (Hr + 8192 + (size_t)m*H_ + (kn-32)*32 + q*8);
              sh[kc&7] = ld16(ph);
              sl[kc&7] = ld16(pl);
            }
            s8v bf0 = ld16(sw +         kc*512 + c*32 + q*8);
            s8v bf1 = ld16(sw + 24576 + kc*512 + c*32 + q*8);
            A0 = MFMA(xh, bf0, A0); A0 = MFMA(xl, bf0, A0);
            A1 = MFMA(xh, bf1, A1); A1 = MFMA(xl, bf1, A1);
          }
          float hn0 = gate_combine(A0, cB0, l);
          float hn1 = gate_combine(A1, cB1, l);
          u16 h0h=f2bf(hn0), h0l=f2bf(hn0 - bf2f(h0h));
          u16 h1h=f2bf(hn1), h1l=f2bf(hn1 - bf2f(h1h));
          u16* Hw = g_H1 + (size_t)(dir*2 + (p1^1))*16384;
          st2c(Hw + (size_t)bo*H_ + hc0, h0h); st2c(Hw + 8192 + (size_t)bo*H_ + hc0, h0l);
          st2c(Hw + (size_t)bo*H_ + hc1, h1h); st2c(Hw + 8192 + (size_t)bo*H_ + hc1, h1l);
          size_t orow = (size_t)(n*10 + row)*16 + bo;
          // OUT1 also write-through: lines must never be dirty in L2 (buffer_inv safety)
          st2c(g_OUT1 + orow*H2 + dir*H_ + hc0, h0h);
          st2c(g_OUT1 + (size_t)800*H2 + orow*H2 + dir*H_ + hc0, h0l);
          st2c(g_OUT1 + orow*H2 + dir*H_ + hc1, h1h);
          st2c(g_OUT1 + (size_t)800*H2 + orow*H2 + dir*H_ + hc1, h1l);
          p1 ^= 1;
        }
      }
      ++ep;
      bar_arrive(ep);
      bar_wait(ep);
    }
  }
}

// =====================  K3: out = OUT1(800x1024 hi/lo) @ Wfc(1024x30000) + bfc =====================
__global__ __launch_bounds__(256,1) void k3(const void* Wfc, const void* bfc, void* out){
  int f32 = (int)g_flag;
  int w = threadIdx.x>>6, l = threadIdx.x&63, q = l>>4, c = l&15, m = l&15;
  int ct = blockIdx.x*4 + w;
  if(ct >= 1875) return;
  int col = ct*16 + c;
  s8v bfr[32];
  #pragma unroll
  for(int kc=0; kc<32; ++kc){
    #pragma unroll
    for(int j=0;j<8;++j) bfr[kc][j] = (short)ldw(Wfc, (size_t)(kc*32+q*8+j)*V_ + col, f32);
  }
  float bi = ldwf(bfc, col, f32);
  for(int rt=0; rt<50; ++rt){
    f4v acc = {0.f,0.f,0.f,0.f};
    const u16* Ah = g_OUT1 + (size_t)(rt*16 + m)*H2;
    const u16* Al = Ah + (size_t)800*H2;
    #pragma unroll
    for(int kc=0; kc<32; ++kc){
      acc = MFMA(ld16(Ah + kc*32 + q*8), bfr[kc], acc);
      acc = MFMA(ld16(Al + kc*32 + q*8), bfr[kc], acc);
    }
    if(f32){
      float* o = (float*)out;
      #pragma unroll
      for(int r=0;r<4;++r) o[(size_t)(rt*16 + q*4 + r)*V_ + col] = acc[r] + bi;
    } else {
      u16* o = (u16*)out;
      #pragma unroll
      for(int r=0;r<4;++r) o[(size_t)(rt*16 + q*4 + r)*V_ + col] = f2bf(acc[r] + bi);
    }
  }
}

// =====================  launcher  =====================
extern "C" void kernel_launch(void* const* d_in, const int* in_sizes, int n_in,
                              void* d_out, int out_size, void* d_ws, size_t ws_size,
                              hipStream_t stream){
  (void)in_sizes; (void)n_in; (void)out_size; (void)d_ws; (void)ws_size;
  const void* img  = d_in[0];
  const int*  caps = (const int*)d_in[1];
  const void* Wh1=d_in[2],  *bh1=d_in[3];
  const void* Wh2=d_in[4],  *bh2=d_in[5];
  const void* Wc1=d_in[6],  *bc1=d_in[7];
  const void* Wc2=d_in[8],  *bc2=d_in[9];
  const void* emb=d_in[10];
  const void* Wih0f=d_in[11], *Whh0f=d_in[12], *b0f=d_in[13];
  const void* Wih0b=d_in[14], *Whh0b=d_in[15], *b0b=d_in[16];
  const void* Wih1f=d_in[17], *Whh1f=d_in[18], *b1f=d_in[19];
  const void* Wih1b=d_in[20], *Whh1b=d_in[21], *b1b=d_in[22];
  const void* Wfc=d_in[23],  *bfc=d_in[24];

  hipLaunchKernelGGL(k0,    dim3(1),       dim3(64),  0, stream, img);
  hipLaunchKernelGGL(k_tok, dim3(800),     dim3(256), 0, stream, caps, emb);
  hipLaunchKernelGGL(k1a,   dim3(32),      dim3(256), 0, stream, img, Wh1, bh1, Wc1, bc1);
  hipLaunchKernelGGL(k1b,   dim3(16),      dim3(256), 0, stream, Wh2, bh2, Wc2, bc2);
  hipLaunchKernelGGL(k2,    dim3(NCOMP+1), dim3(128), 0, stream,
                     Wih0f, Whh0f, b0f, Wih0b, Whh0b, b0b,
                     Wih1f, Whh1f, b1f, Wih1b, Whh1b, b1b);
  hipLaunchKernelGGL(k3,    dim3(469),     dim3(256), 0, stream, Wfc, bfc, d_out);
}

// Round 3
// 3612.248 us; speedup vs baseline: 4.1011x; 1.5660x over previous
//
#include <hip/hip_runtime.h>

typedef unsigned short u16;
typedef unsigned int   u32;
typedef unsigned long long u64;
typedef __attribute__((ext_vector_type(8))) short s8v;   // 8 x bf16 (4 VGPRs)
typedef __attribute__((ext_vector_type(4))) float f4v;   // MFMA accumulator

#define DEVI __device__ __forceinline__

// ---- problem constants ----
#define B_  16
#define N_  5
#define T_  10
#define H_  512
#define E_  250
#define V_  30000
#define F_  2048
#define FH  2048   // 4H
#define H2  1024   // 2H
#define NCOMP 128  // compute blocks: dir(2) x 64 col-groups, 2 waves each

// ---- static device scratch (no d_ws dependence) ----
__device__ u32   g_flag;                  // 1 = inputs are float32, 0 = bf16
__device__ u32   g_slot[NCOMP];           // barrier arrival epochs (per block)
__device__ __attribute__((aligned(64))) u16   g_H0[4*2*16*512];   // [(dir*2+par)][plane][16][512]
__device__ __attribute__((aligned(64))) u16   g_H1[4*2*16*512];
__device__ __attribute__((aligned(64))) float g_cinit[16*512];
__device__ __attribute__((aligned(64))) u16   g_A1[2*2*16*1024];  // [which][plane][16][1024]
__device__ __attribute__((aligned(64))) u16   g_X1[2*2*10*16*1024]; // [callpar][plane][row*16+b][1024]
__device__ __attribute__((aligned(64))) u16   g_OUT1[2*800*1024]; // [plane][orow][1024]
__device__ __attribute__((aligned(64))) u16   g_TOK[800*256];     // [(b*5+n)*10+r][256] bf16

DEVI f4v MFMA(s8v a, s8v b, f4v c){ return __builtin_amdgcn_mfma_f32_16x16x32_bf16(a,b,c,0,0,0); }
DEVI float bf2f(u16 u){ union{u32 i; float f;} v; v.i = ((u32)u)<<16; return v.f; }
DEVI u16 f2bf(float f){ union{float f; u32 i;} v; v.f = f; u32 i = v.i + 0x7fffu + ((v.i>>16)&1u); return (u16)(i>>16); }
DEVI float sigm(float x){ return 1.0f/(1.0f+__expf(-x)); }
DEVI float tanhfast(float x){ float e = __expf(2.0f*x); return 1.0f - 2.0f/(e+1.0f); }

DEVI s8v ld16(const u16* p){ return *(const s8v*)p; }                 // 16B-aligned, cached
DEVI s8v ld16u(const u16* p){ s8v a; __builtin_memcpy(&a, p, 16); return a; }

// bypassing 16B load issue (sc0 sc1 -> served at mall, no stale L1/L2). Completion is
// tracked manually via counted vmcnt waits (waitv/waitv2 tie the wait to the dest regs
// so consuming MFMAs cannot be scheduled above the wait).
DEVI void ldc(s8v& d, const u16* p){
  asm volatile("global_load_dwordx4 %0, %1, off sc0 sc1" : "=v"(d) : "v"(p));
}
template<int N> DEVI void waitv(s8v& a){
  asm volatile("s_waitcnt vmcnt(%1)" : "+v"(a) : "n"(N));
}
template<int N> DEVI void waitv2(s8v& a, s8v& b){
  asm volatile("s_waitcnt vmcnt(%2)" : "+v"(a), "+v"(b) : "n"(N));
}

// coherent write-through 2B store (sc0 sc1): visible at mall, never dirty in L2
DEVI void st2c(u16* p, u16 v){
  asm volatile("global_store_short %0, %1, off sc0 sc1" :: "v"(p), "v"((u32)v) : "memory");
}

// dtype-flexible element accessors (flag is wave-uniform)
DEVI u16 ldw(const void* W, size_t idx, int f32){
  return f32 ? f2bf(((const float*)W)[idx]) : ((const u16*)W)[idx];
}
DEVI float ldwf(const void* W, size_t idx, int f32){
  return f32 ? ((const float*)W)[idx] : bf2f(((const u16*)W)[idx]);
}
DEVI s8v ldA8(const void* A, size_t idx, int f32){
  if(f32){
    const float* p = (const float*)A + idx;
    s8v a;
    #pragma unroll
    for(int j=0;j<8;++j) a[j] = (short)f2bf(p[j]);
    return a;
  }
  return ld16u((const u16*)A + idx);
}
DEVI s8v gatherBf(const void* W, int ld, int row0, int col, int f32){
  s8v r;
  #pragma unroll
  for(int j=0;j<8;++j) r[j] = (short)ldw(W, (size_t)(row0+j)*ld + col, f32);
  return r;
}

// repeat macros (manual unroll keeps every index/template-arg a literal constant)
#define RPT4(M,b)  M(b) M((b)+1) M((b)+2) M((b)+3)
#define RPT8(M,b)  RPT4(M,b) RPT4(M,(b)+4)
#define RPT16(M,b) RPT8(M,b) RPT8(M,(b)+8)

// =====================  K0: dtype sniff + barrier state reset  =====================
__global__ __launch_bounds__(64) void k0(const void* img){
  int l = threadIdx.x;
  const u16* p = (const u16*)img;
  int bad = 0;
  #pragma unroll
  for(int i=0;i<4;++i){
    float v = bf2f(p[l + 64*i]);      // f32 data => half these are mantissa garbage
    if(!(fabsf(v) <= 1e4f)) bad = 1;  // catches huge exponents AND NaN
  }
  unsigned long long mb = __ballot(bad);
  g_slot[l] = 0u; g_slot[l+64] = 0u;
  if(l==0){ g_flag = (mb != 0ull) ? 1u : 0u; }
}

// =====================  K_tok: compact bf16 token-embedding table  =====================
__global__ __launch_bounds__(256) void k_tok(const int* caps, const void* emb){
  int f32 = (int)g_flag;
  int idx = blockIdx.x*256 + threadIdx.x;     // 0 .. 800*256-1
  int bnr = idx>>8, e = idx&255;
  int tok = caps[bnr];
  u16 v = (e < E_) ? ldw(emb, (size_t)tok*E_ + e, f32) : (u16)0;
  g_TOK[idx] = v;
}

// =====================  K1a: A1 = relu(img@Wh1+bh1), C1 = relu(img@Wc1+bc1) =====================
__global__ __launch_bounds__(256) void k1a(const void* img, const void* Wh1, const void* bh1,
                                           const void* Wc1, const void* bc1){
  int f32 = (int)g_flag;
  int w = threadIdx.x>>6, l = threadIdx.x&63, q = l>>4, c = l&15, m = l&15;
  int widx = blockIdx.x*4 + w;         // 0..127
  int which = widx>>6;                 // 0=h path, 1=c path
  int ct    = widx&63;                 // 64 col tiles
  const void* W    = which? Wc1 : Wh1;
  const void* bias = which? bc1 : bh1;
  int col = ct*16 + c;
  f4v acc = {0.f,0.f,0.f,0.f};
  for(int kc=0; kc<64; ++kc){
    s8v a = ldA8(img, (size_t)m*F_ + kc*32 + q*8, f32);
    s8v b = gatherBf(W, H2, kc*32+q*8, col, f32);
    acc = MFMA(a,b,acc);
  }
  float bi = ldwf(bias, col, f32);
  #pragma unroll
  for(int r=0;r<4;++r){
    float v = fmaxf(acc[r]+bi, 0.f);
    u16 hi = f2bf(v); u16 lo = f2bf(v - bf2f(hi));
    int rowb = q*4+r;
    g_A1[(size_t)(which*2+0)*B_*H2 + (size_t)rowb*H2 + col] = hi;
    g_A1[(size_t)(which*2+1)*B_*H2 + (size_t)rowb*H2 + col] = lo;
  }
}

// =====================  K1b: h,c = relu(A1@Wh2+bh2) etc; init H bufs (parity 0), cinit =====================
__global__ __launch_bounds__(256) void k1b(const void* Wh2, const void* bh2,
                                           const void* Wc2, const void* bc2){
  int f32 = (int)g_flag;
  int w = threadIdx.x>>6, l = threadIdx.x&63, q = l>>4, c = l&15, m = l&15;
  int widx = blockIdx.x*4 + w;         // 0..63
  int which = widx>>5;                 // 0=h, 1=c
  int ct    = widx&31;                 // 32 col tiles (H=512)
  const void* W    = which? Wc2 : Wh2;
  const void* bias = which? bc2 : bh2;
  const u16* Ab    = g_A1 + (size_t)which*2*B_*H2;
  int col = ct*16 + c;
  f4v acc = {0.f,0.f,0.f,0.f};
  for(int kc=0; kc<32; ++kc){
    s8v ah = ld16(Ab + (size_t)m*H2 + kc*32 + q*8);
    s8v al = ld16(Ab + (size_t)B_*H2 + (size_t)m*H2 + kc*32 + q*8);
    s8v b  = gatherBf(W, H_, kc*32+q*8, col, f32);
    acc = MFMA(ah,b,acc);
    acc = MFMA(al,b,acc);
  }
  float bi = ldwf(bias, col, f32);
  #pragma unroll
  for(int r=0;r<4;++r){
    float v = fmaxf(acc[r]+bi, 0.f);
    int rowb = q*4+r;
    if(which==0){
      u16 hi = f2bf(v); u16 lo = f2bf(v - bf2f(hi));
      #pragma unroll
      for(int dir=0; dir<2; ++dir){
        size_t base = (size_t)(dir*2+0)*16384;      // parity 0
        g_H0[base + 0*8192 + rowb*512 + col] = hi;  g_H0[base + 1*8192 + rowb*512 + col] = lo;
        g_H1[base + 0*8192 + rowb*512 + col] = hi;  g_H1[base + 1*8192 + rowb*512 + col] = lo;
      }
    } else {
      g_cinit[(size_t)rowb*H_ + col] = v;
    }
  }
}

// ========== dataflow flags (BSP-equivalent, no coordinator, no cache invalidation) =========
// publish(ep): both waves drain write-through stores (mall-visible), join, store slot=ep.
// poll(ep): each wave independently spins until all 128 slots >= ep (lane l owns 2 slots).
// Invariant: a block computes superstep i only after all blocks completed i-1 => compute
// phases never overlap across superstep indices (same as the old full barrier).
DEVI void flag_publish(u32 ep){
  asm volatile("s_waitcnt vmcnt(0)" ::: "memory");   // data stores acked at mall
  __syncthreads();                                    // both waves of the block done
  if(threadIdx.x==0)
    __hip_atomic_store(&g_slot[blockIdx.x], ep, __ATOMIC_RELAXED, __HIP_MEMORY_SCOPE_SYSTEM);
}
DEVI void flag_poll(u32 ep){
  int l = threadIdx.x & 63;
  for(;;){
    u32 a = __hip_atomic_load(&g_slot[l],    __ATOMIC_RELAXED, __HIP_MEMORY_SCOPE_SYSTEM);
    u32 b = __hip_atomic_load(&g_slot[l+64], __ATOMIC_RELAXED, __HIP_MEMORY_SCOPE_SYSTEM);
    if(__all((int)(a>=ep && b>=ep))) break;
    __builtin_amdgcn_s_sleep(1);
  }
  asm volatile("s_waitcnt vmcnt(0)" ::: "memory");   // clean vmcnt before counted phases
}

// gate combine: acc holds G[batch=4q+r][col c], cols = gate(c>>2) x hcol(c&3).
DEVI float gate_combine(f4v acc, float& cs, int l){
  int base = (l & 48) | (l & 3);
  int sel  = (l >> 2) & 3;
  float G[4];
  #pragma unroll
  for(int gg=0; gg<4; ++gg){
    int src = base | (gg<<2);
    float a0 = __shfl(acc[0], src, 64);
    float a1 = __shfl(acc[1], src, 64);
    float a2 = __shfl(acc[2], src, 64);
    float a3 = __shfl(acc[3], src, 64);
    float x = (sel&1)? a1 : a0;
    float y = (sel&1)? a3 : a2;
    G[gg] = (sel&2)? y : x;
  }
  float iG = sigm(G[0]);
  float fG = sigm(G[1]);
  float gG = tanhfast(G[2]);
  float oG = sigm(G[3]);
  cs = fG*cs + iG*gG;
  return oG * tanhfast(cs);
}

// =====================  K2: persistent pipelined bilstm2 x 50  =====================
// 128 blocks x 128 threads (2 waves). Block: dir = blk>=64, 8 h-cols. wave0 = layer-0
// engine (weights in VGPRs), wave1 = layer-1 engine lagged one call ([Wih1;Whh1] in 96KB
// LDS). 285 supersteps. Shared state via sc0sc1 write-through stores + counted-vmcnt
// pipelined bypass loads. Poll-overlap: wave0's emb phase and (s>0) wave1's whole X1
// phase run BEFORE the flag poll.
__global__ __launch_bounds__(128) void k2(const void* Wih0f, const void* Whh0f, const void* b0f,
                                          const void* Wih0b, const void* Whh0b, const void* b0b,
                                          const void* Wih1f, const void* Whh1f, const void* b1f,
                                          const void* Wih1b, const void* Whh1b, const void* b1b){
  __shared__ u16 sw[2*24576];                  // 96 KB: [tile][kc48][c16][q4][j8]
  int tid = threadIdx.x;
  int blk = blockIdx.x;
  int f32 = (int)g_flag;
  int wv  = tid>>6;                            // 0 = layer-0 wave, 1 = layer-1 wave
  int l   = tid&63;
  int q = l>>4, c = l&15, m = l&15;
  int dir = blk>>6; int blkd = blk&63;
  int hb  = blkd*8;                            // 8 owned h-cols
  int gc0 = (c>>2)*512 + hb + (c&3);           // lane's G-column, tile 0
  int gc1 = gc0 + 4;                           // tile 1
  int bo  = q*4 + (c>>2);                      // owned batch row
  int hc0 = hb + (c&3), hc1 = hc0 + 4;         // owned h-cols

  const void* Wih0 = dir? Wih0b : Wih0f;
  const void* Whh0 = dir? Whh0b : Whh0f;
  const void* b0   = dir? b0b   : b0f;
  const void* Wih1 = dir? Wih1b : Wih1f;
  const void* Whh1 = dir? Whh1b : Whh1f;
  const void* b1   = dir? b1b   : b1f;

  // ---- layer-1 B-fragments for both tiles in LDS ----
  for(int tt=0; tt<2; ++tt){
    int gb = hb + tt*4;
    for(int ii=tid; ii<24576; ii+=128){
      int kc=ii>>9, rem=ii&511, cc=rem>>5, qq=(rem>>3)&3, j=ii&7;
      int gc = (cc>>2)*512 + gb + (cc&3);
      int rowk = kc*32+qq*8+j;
      sw[tt*24576+ii] = (rowk < H2) ? ldw(Wih1, (size_t)rowk*FH + gc, f32)
                                    : ldw(Whh1, (size_t)(rowk-H2)*FH + gc, f32);
    }
  }

  // ---- per-wave persistent state ----
  s8v w0a[16], w0b[16], wxa[8], wxb[8];        // wave0 only: layer-0 B-frags in regs
  float cA0=0.f, cA1=0.f, biasA0=0.f, biasA1=0.f;   // wave0 (layer-0 cell state)
  float cB0=0.f, cB1=0.f, biasB0=0.f, biasB1=0.f;   // wave1 (layer-1 cell state)
  if(wv==0){
    #pragma unroll
    for(int kc=0;kc<16;++kc){
      #pragma unroll
      for(int j=0;j<8;++j){
        int rowk = kc*32+q*8+j;
        w0a[kc][j] = (short)ldw(Whh0, (size_t)rowk*FH + gc0, f32);
        w0b[kc][j] = (short)ldw(Whh0, (size_t)rowk*FH + gc1, f32);
      }
    }
    #pragma unroll
    for(int kc=0;kc<8;++kc){
      #pragma unroll
      for(int j=0;j<8;++j){
        int rowk = kc*32+q*8+j;
        wxa[kc][j] = (rowk<E_)? (short)ldw(Wih0, (size_t)rowk*FH + gc0, f32) : (short)0;
        wxb[kc][j] = (rowk<E_)? (short)ldw(Wih0, (size_t)rowk*FH + gc1, f32) : (short)0;
      }
    }
    biasA0 = ldwf(b0, gc0, f32); biasA1 = ldwf(b0, gc1, f32);
    cA0 = g_cinit[(size_t)bo*H_ + hc0]; cA1 = g_cinit[(size_t)bo*H_ + hc1];
  } else {
    biasB0 = ldwf(b1, gc0, f32); biasB1 = ldwf(b1, gc1, f32);
    cB0 = g_cinit[(size_t)bo*H_ + hc0]; cB1 = g_cinit[(size_t)bo*H_ + hc1];
  }
  __syncthreads();

  u32 ep = 0;
  int p0 = 0, p1 = 0;
  // superstep schedule: layer-0 runs call k, layer-1 runs call k-1 (lengths are
  // non-decreasing so layer-1 never starves). k==50 is the pure layer-1 tail.
  for(int k=0; k<=50; ++k){
    int Lk = (k<50) ? (k/5 + 1) : 10;
    int Lp = (k==0) ? 0 : ((k-1)/5 + 1);
    int n0 = k - (k/5)*5;
    int km = k-1;
    int n1 = (k>0) ? (km - (km/5)*5) : 0;
    for(int s=0; s<Lk; ++s){
      if(wv==0){
        if(k<50){
          int row = dir ? (Lk-1-s) : s;
          const u16* er = g_TOK + ((size_t)(m*N_ + n0)*T_ + row)*256;
          const u16* Hr = g_H0 + (size_t)(dir*2 + p0)*16384;
          f4v A0 = {biasA0,biasA0,biasA0,biasA0};
          f4v A1 = {biasA1,biasA1,biasA1,biasA1};
          // --- emb phase (static TOK, plain cached loads) BEFORE the poll ---
          #pragma unroll
          for(int kc=0;kc<8;++kc){
            s8v a = ld16(er + kc*32 + q*8);
            A0 = MFMA(a, wxa[kc], A0); A1 = MFMA(a, wxb[kc], A1);
          }
          flag_poll(ep);
          // --- counted bypass H stream: 32 loads (f: plane=f&1, kc=f>>1), depth 16 ---
          s8v hst[16];
#define H0ISS(f) ldc(hst[(f)], Hr + (((f)&1)?8192u:0u) + (size_t)m*H_ + (((f)>>1)*32) + q*8);
#define H0STEP(f) { \
          waitv<(((f)<16)?15:(31-(f)))>(hst[(f)&15]); \
          A0 = MFMA(hst[(f)&15], w0a[(f)>>1], A0); \
          A1 = MFMA(hst[(f)&15], w0b[(f)>>1], A1); \
          if((f)+16<32) ldc(hst[(f)&15], Hr + (((f)&1)?8192u:0u) + (size_t)m*H_ + (((((f)+16))>>1)*32) + q*8); }
          RPT16(H0ISS,0)
          RPT16(H0STEP,0) RPT16(H0STEP,16)
          float hn0 = gate_combine(A0, cA0, l);
          float hn1 = gate_combine(A1, cA1, l);
          u16 h0h=f2bf(hn0), h0l=f2bf(hn0 - bf2f(h0h));
          u16 h1h=f2bf(hn1), h1l=f2bf(hn1 - bf2f(h1h));
          u16* Hw = g_H0 + (size_t)(dir*2 + (p0^1))*16384;
          st2c(Hw + (size_t)bo*H_ + hc0, h0h); st2c(Hw + 8192 + (size_t)bo*H_ + hc0, h0l);
          st2c(Hw + (size_t)bo*H_ + hc1, h1h); st2c(Hw + 8192 + (size_t)bo*H_ + hc1, h1l);
          u16* Xw = g_X1 + (size_t)(k&1)*327680;          // call-parity double buffer
          size_t xr = ((size_t)row*16 + bo)*H2 + dir*H_;
          st2c(Xw + xr + hc0, h0h); st2c(Xw + 163840 + xr + hc0, h0l);
          st2c(Xw + xr + hc1, h1h); st2c(Xw + 163840 + xr + hc1, h1l);
          p0 ^= 1;
        }
      } else {
        if(k>0 && s<Lp){
          int row = dir ? (Lp-1-s) : s;
          const u16* Xr  = g_X1 + (size_t)(km&1)*327680 + ((size_t)row*16)*H2;
          const u16* Xr2 = Xr + 163840;
          const u16* Hr1 = g_H1 + (size_t)(dir*2 + p1)*16384;
          f4v A0 = {biasB0,biasB0,biasB0,biasB0};
          f4v A1 = {biasB1,biasB1,biasB1,biasB1};
          s8v sh[12], sl[12];
          // X1 of call k-1 is stable during call k's steps for s>0 (same-parity writers
          // only exist at call k+1, which the barrier forbids). At s==0 the last X1 rows
          // were written in superstep ep-1 -> must poll first.
          if(s==0) flag_poll(ep);
          // --- counted bypass X stream: pairs kc=0..31 (hi,lo), depth 12 pairs ---
#define XISS(kc) { ldc(sh[(kc)], Xr + (size_t)m*H2 + ((kc)*32) + q*8); \
                   ldc(sl[(kc)], Xr2 + (size_t)m*H2 + ((kc)*32) + q*8); }
#define XSTEP(kc) { \
          waitv2<(((kc)<20)?22:(62-2*(kc)))>(sh[(kc)%12], sl[(kc)%12]); \
          s8v bf0 = ld16(sw + (kc)*512 + c*32 + q*8); \
          s8v bf1 = ld16(sw + 24576 + (kc)*512 + c*32 + q*8); \
          A0 = MFMA(sh[(kc)%12], bf0, A0); A0 = MFMA(sl[(kc)%12], bf0, A0); \
          A1 = MFMA(sh[(kc)%12], bf1, A1); A1 = MFMA(sl[(kc)%12], bf1, A1); \
          if((kc)+12<32){ ldc(sh[(kc)%12], Xr + (size_t)m*H2 + (((kc)+12)*32) + q*8); \
                          ldc(sl[(kc)%12], Xr2 + (size_t)m*H2 + (((kc)+12)*32) + q*8); } }
          RPT8(XISS,0) RPT4(XISS,8)
          RPT16(XSTEP,0) RPT16(XSTEP,16)
          if(s>0) flag_poll(ep);
          // --- counted bypass H1 stream: pairs h=0..15 (hi,lo), depth 12 pairs ---
#define H1ISS(h) { ldc(sh[(h)], Hr1 + (size_t)m*H_ + ((h)*32) + q*8); \
                   ldc(sl[(h)], Hr1 + 8192 + (size_t)m*H_ + ((h)*32) + q*8); }
#define H1STEP(h) { \
          waitv2<(((h)<4)?22:(30-2*(h)))>(sh[(h)%12], sl[(h)%12]); \
          s8v bf0 = ld16(sw + (32+(h))*512 + c*32 + q*8); \
          s8v bf1 = ld16(sw + 24576 + (32+(h))*512 + c*32 + q*8); \
          A0 = MFMA(sh[(h)%12], bf0, A0); A0 = MFMA(sl[(h)%12], bf0, A0); \
          A1 = MFMA(sh[(h)%12], bf1, A1); A1 = MFMA(sl[(h)%12], bf1, A1); \
          if((h)+12<16){ ldc(sh[(h)%12], Hr1 + (size_t)m*H_ + (((h)+12)*32) + q*8); \
                         ldc(sl[(h)%12], Hr1 + 8192 + (size_t)m*H_ + (((h)+12)*32) + q*8); } }
          RPT8(H1ISS,0) RPT4(H1ISS,8)
          RPT16(H1STEP,0)
          float hn0 = gate_combine(A0, cB0, l);
          float hn1 = gate_combine(A1, cB1, l);
          u16 h0h=f2bf(hn0), h0l=f2bf(hn0 - bf2f(h0h));
          u16 h1h=f2bf(hn1), h1l=f2bf(hn1 - bf2f(h1h));
          u16* Hw = g_H1 + (size_t)(dir*2 + (p1^1))*16384;
          st2c(Hw + (size_t)bo*H_ + hc0, h0h); st2c(Hw + 8192 + (size_t)bo*H_ + hc0, h0l);
          st2c(Hw + (size_t)bo*H_ + hc1, h1h); st2c(Hw + 8192 + (size_t)bo*H_ + hc1, h1l);
          size_t orow = (size_t)(n1*10 + row)*16 + bo;
          st2c(g_OUT1 + orow*H2 + dir*H_ + hc0, h0h);
          st2c(g_OUT1 + (size_t)800*H2 + orow*H2 + dir*H_ + hc0, h0l);
          st2c(g_OUT1 + orow*H2 + dir*H_ + hc1, h1h);
          st2c(g_OUT1 + (size_t)800*H2 + orow*H2 + dir*H_ + hc1, h1l);
          p1 ^= 1;
        }
      }
      flag_publish(ep+1);
      ++ep;
    }
  }
}

// =====================  K3: out = OUT1(800x1024 hi/lo) @ Wfc(1024x30000) + bfc =====================
__global__ __launch_bounds__(256,1) void k3(const void* Wfc, const void* bfc, void* out){
  int f32 = (int)g_flag;
  int w = threadIdx.x>>6, l = threadIdx.x&63, q = l>>4, c = l&15, m = l&15;
  int ct = blockIdx.x*4 + w;
  if(ct >= 1875) return;
  int col = ct*16 + c;
  s8v bfr[32];
  #pragma unroll
  for(int kc=0; kc<32; ++kc){
    #pragma unroll
    for(int j=0;j<8;++j) bfr[kc][j] = (short)ldw(Wfc, (size_t)(kc*32+q*8+j)*V_ + col, f32);
  }
  float bi = ldwf(bfc, col, f32);
  for(int rt=0; rt<50; ++rt){
    f4v acc = {0.f,0.f,0.f,0.f};
    const u16* Ah = g_OUT1 + (size_t)(rt*16 + m)*H2;
    const u16* Al = Ah + (size_t)800*H2;
    #pragma unroll
    for(int kc=0; kc<32; ++kc){
      acc = MFMA(ld16(Ah + kc*32 + q*8), bfr[kc], acc);
      acc = MFMA(ld16(Al + kc*32 + q*8), bfr[kc], acc);
    }
    if(f32){
      float* o = (float*)out;
      #pragma unroll
      for(int r=0;r<4;++r) o[(size_t)(rt*16 + q*4 + r)*V_ + col] = acc[r] + bi;
    } else {
      u16* o = (u16*)out;
      #pragma unroll
      for(int r=0;r<4;++r) o[(size_t)(rt*16 + q*4 + r)*V_ + col] = f2bf(acc[r] + bi);
    }
  }
}

// =====================  launcher  =====================
extern "C" void kernel_launch(void* const* d_in, const int* in_sizes, int n_in,
                              void* d_out, int out_size, void* d_ws, size_t ws_size,
                              hipStream_t stream){
  (void)in_sizes; (void)n_in; (void)out_size; (void)d_ws; (void)ws_size;
  const void* img  = d_in[0];
  const int*  caps = (const int*)d_in[1];
  const void* Wh1=d_in[2],  *bh1=d_in[3];
  const void* Wh2=d_in[4],  *bh2=d_in[5];
  const void* Wc1=d_in[6],  *bc1=d_in[7];
  const void* Wc2=d_in[8],  *bc2=d_in[9];
  const void* emb=d_in[10];
  const void* Wih0f=d_in[11], *Whh0f=d_in[12], *b0f=d_in[13];
  const void* Wih0b=d_in[14], *Whh0b=d_in[15], *b0b=d_in[16];
  const void* Wih1f=d_in[17], *Whh1f=d_in[18], *b1f=d_in[19];
  const void* Wih1b=d_in[20], *Whh1b=d_in[21], *b1b=d_in[22];
  const void* Wfc=d_in[23],  *bfc=d_in[24];

  hipLaunchKernelGGL(k0,    dim3(1),     dim3(64),  0, stream, img);
  hipLaunchKernelGGL(k_tok, dim3(800),   dim3(256), 0, stream, caps, emb);
  hipLaunchKernelGGL(k1a,   dim3(32),    dim3(256), 0, stream, img, Wh1, bh1, Wc1, bc1);
  hipLaunchKernelGGL(k1b,   dim3(16),    dim3(256), 0, stream, Wh2, bh2, Wc2, bc2);
  hipLaunchKernelGGL(k2,    dim3(NCOMP), dim3(128), 0, stream,
                     Wih0f, Whh0f, b0f, Wih0b, Whh0b, b0b,
                     Wih1f, Whh1f, b1f, Wih1b, Whh1b, b1b);
  hipLaunchKernelGGL(k3,    dim3(469),   dim3(256), 0, stream, Wfc, bfc, d_out);
}